// Round 7
// baseline (380.687 us; speedup 1.0000x reference)
//
#include <hip/hip_runtime.h>
#include <hip/hip_bf16.h>
#include <stdint.h>
#include <math.h>

// Problem constants
#define B_    2
#define T_    2048
#define C_    2048
#define H_    16
#define D_    128
#define NQKV  6144      // 3*C
#define BT_   4096      // B*T

typedef __attribute__((ext_vector_type(8))) short  short8;   // 8 bf16 (4 VGPR) MFMA A/B frag
typedef __attribute__((ext_vector_type(4))) short  short4_;  // 4 bf16 (8B)
typedef __attribute__((ext_vector_type(4))) float  float4_;  // MFMA C/D frag

__device__ __forceinline__ unsigned short f2bf(float f) {
  union { float f; unsigned int u; } v; v.f = f;
  unsigned int u = v.u;
  return (unsigned short)((u + 0x7FFFu + ((u >> 16) & 1u)) >> 16);  // RNE
}
__device__ __forceinline__ float bf2f(unsigned short u) {
  union { unsigned int i; float f; } v; v.i = ((unsigned int)u) << 16;
  return v.f;
}
// packed fp32x2 -> bf16x2
__device__ __forceinline__ void pk2(short4_& dst, int idx2, float a, float b) {
  union { __hip_bfloat162 h2; struct { short x, y; } s; } u;
  u.h2 = __float22bfloat162_rn(make_float2(a, b));
  dst[idx2 * 2]     = u.s.x;
  dst[idx2 * 2 + 1] = u.s.y;
}

// async global->LDS, 16B per lane.  HW dest = wave-uniform base + lane*16,
// so LDS offsets must be contiguous in thread order (they are: base + tid*16).
__device__ __forceinline__ void async_cp16(const unsigned short* g, unsigned short* l) {
  __builtin_amdgcn_global_load_lds((__attribute__((address_space(1))) void*)g,
                                   (__attribute__((address_space(3))) void*)l,
                                   16, 0, 0);
}

// ----------------------------- fused fp32->bf16 (all 3 inputs) + trig table
// Blocks 0..12287: bf16 conversion.  Blocks 12288..12799: RoPE trig table,
// INTERLEAVED float2: cst[t*64+d] = {cos, sin}((sp+t) * 10000^(-d/64)).
// Accurate sinf/cosf live HERE (tiny register footprint -> inlined; round-2
// lesson: outlined trig inside the fat GEMM caused a scratch-write storm).
__global__ __launch_bounds__(256) void cvt_all(const float* __restrict__ x,
                                               const float* __restrict__ wqkv,
                                               const float* __restrict__ wproj,
                                               const int* __restrict__ sp_ptr,
                                               unsigned short* __restrict__ out,
                                               float2* __restrict__ cst) {
  if (blockIdx.x >= 12288) {
    int j = (blockIdx.x - 12288) * 256 + threadIdx.x;   // 0..131071
    int d = j & 63;
    const float L2F = -0.20762050593046013f;  // -log2(10000)/64
    float fr = exp2f((float)d * L2F);
    float ang = (float)(sp_ptr[0] + (j >> 6)) * fr;
    cst[j] = make_float2(cosf(ang), sinf(ang));
    return;
  }
  int i = (blockIdx.x * 256 + threadIdx.x) * 8;   // 0 .. 25165824-8
  const float* src; int off;
  if (i < 8388608)       { src = x;     off = i; }
  else if (i < 20971520) { src = wqkv;  off = i - 8388608; }
  else                   { src = wproj; off = i - 20971520; }
  const float4_* p = (const float4_*)(src + off);
  float4_ a = p[0], b = p[1];
  short8 o;
  o[0] = (short)f2bf(a[0]); o[1] = (short)f2bf(a[1]);
  o[2] = (short)f2bf(a[2]); o[3] = (short)f2bf(a[3]);
  o[4] = (short)f2bf(b[0]); o[5] = (short)f2bf(b[1]);
  o[6] = (short)f2bf(b[2]); o[7] = (short)f2bf(b[3]);
  *(short8*)(out + i) = o;
}

// ------------------------------------------------------- GEMM  C = A * B^T
// (frozen m97-structure 128x128 kernel — used for the projection GEMM)
template <bool F32OUT>
__global__ __launch_bounds__(256) void gemm_bt(const unsigned short* __restrict__ A,
                                               const unsigned short* __restrict__ Bm,
                                               void* __restrict__ Cout,
                                               int M, int N, int K) {
  __shared__ __align__(16) unsigned short As[128 * 64];
  __shared__ __align__(16) unsigned short Bs[128 * 64];
  const int tid  = threadIdx.x;
  const int lane = tid & 63;
  const int col16 = lane & 15, quad = lane >> 4;
  const int wave = tid >> 6;
  const int wm = wave >> 1, wn = wave & 1;
  const int m0 = blockIdx.y * 128, n0 = blockIdx.x * 128;

  float4_ acc[4][4] = {};

  #pragma unroll 1
  for (int k0 = 0; k0 < K; k0 += 64) {
    __syncthreads();
    #pragma unroll
    for (int i = 0; i < 4; ++i) {
      int P   = i * 256 + tid;
      int row = P >> 3;                    // tile row 0..127
      int kc  = (P & 7) ^ (row & 7);       // logical chunk for this phys slot
      async_cp16(A  + (size_t)(m0 + row) * K + k0 + kc * 8, As + P * 8);
      async_cp16(Bm + (size_t)(n0 + row) * K + k0 + kc * 8, Bs + P * 8);
    }
    __syncthreads();
    #pragma unroll
    for (int ks = 0; ks < 2; ++ks) {
      short8 af[4], bf[4];
      #pragma unroll
      for (int i = 0; i < 4; ++i) {
        int ra = wm * 64 + i * 16 + col16;
        int ca = ((ks * 4 + quad) ^ (ra & 7)) * 8;
        af[i] = *(const short8*)(As + ra * 64 + ca);
        int rb = wn * 64 + i * 16 + col16;
        int cb = ((ks * 4 + quad) ^ (rb & 7)) * 8;
        bf[i] = *(const short8*)(Bs + rb * 64 + cb);
      }
      #pragma unroll
      for (int i = 0; i < 4; ++i)
        #pragma unroll
        for (int j = 0; j < 4; ++j)
          acc[i][j] = __builtin_amdgcn_mfma_f32_16x16x32_bf16(af[i], bf[j], acc[i][j], 0, 0, 0);
    }
  }

  // epilogue: C/D layout col=lane&15 (n), row=quad*4+reg (m)
  #pragma unroll
  for (int i = 0; i < 4; ++i) {
    int mg = m0 + wm * 64 + i * 16 + quad * 4;
    #pragma unroll
    for (int j = 0; j < 4; ++j) {
      int ng = n0 + wn * 64 + j * 16 + col16;
      #pragma unroll
      for (int r = 0; r < 4; ++r) {
        if constexpr (F32OUT)
          ((float*)Cout)[(size_t)(mg + r) * N + ng] = acc[i][j][r];
        else
          ((unsigned short*)Cout)[(size_t)(mg + r) * N + ng] = f2bf(acc[i][j][r]);
      }
    }
  }
}

// ---------------------------------------- GEMM1 + fused RoPE/split/V-transpose
// Same main loop as gemm_bt (M=4096, N=6144, K=2048 fixed) with one change:
// the B-fragment row mapping per j is  rb = wn*32 + (j&1)*16 + (j>>1)*64 + c16,
// so that acc[i][j] and acc[i][j+2] hold the RoPE pair (d, d+64) IN THE SAME
// LANE.  Each 128-wide n-tile is exactly one head of Q, K or V, so the
// epilogue mode is block-uniform.
//
// Round-6 lesson: the Q/K RoPE-from-registers epilogue kept acc (64 VGPR)
// live across the whole trig+scatter-store sequence -> VGPR 112 -> 4 blk/CU
// (vs gemm_bt's 80 / 5 blk/CU); sched_barrier fences couldn't fix a
// live-range problem.  Now ALL THREE regions use the same two-phase shape:
//   phase 1: acc -> LDS tile (bf16, chunk-swizzled), acc DIES here
//   phase 2: coalesced LDS-row reads -> (RoPE for Q/K) -> 16B global stores
// Peak live set ~ acc + few temps, so the allocator can return to ~80-90
// VGPR and the main loop regains 5 blocks/CU.
__global__ __launch_bounds__(256) void gemm_qkv(const unsigned short* __restrict__ A,
                                                const unsigned short* __restrict__ Bm,
                                                const float2* __restrict__ cst,
                                                unsigned short* __restrict__ q_r,
                                                unsigned short* __restrict__ k_r,
                                                unsigned short* __restrict__ v_t) {
  __shared__ __align__(16) unsigned short S[16384];  // As = S[0:8192), Bs = S[8192:16384)
  unsigned short* As = S;
  unsigned short* Bs = S + 8192;
  const int tid  = threadIdx.x;
  const int lane = tid & 63;
  const int col16 = lane & 15, quad = lane >> 4;
  const int wave = tid >> 6;
  const int wm = wave >> 1, wn = wave & 1;
  const int m0 = blockIdx.y * 128, n0 = blockIdx.x * 128;

  float4_ acc[4][4] = {};

  #pragma unroll 1
  for (int k0 = 0; k0 < C_; k0 += 64) {
    __syncthreads();
    #pragma unroll
    for (int i = 0; i < 4; ++i) {
      int P   = i * 256 + tid;
      int row = P >> 3;
      int kc  = (P & 7) ^ (row & 7);
      async_cp16(A  + (size_t)(m0 + row) * C_ + k0 + kc * 8, As + P * 8);
      async_cp16(Bm + (size_t)(n0 + row) * C_ + k0 + kc * 8, Bs + P * 8);
    }
    __syncthreads();
    #pragma unroll
    for (int ks = 0; ks < 2; ++ks) {
      short8 af[4], bf[4];
      #pragma unroll
      for (int i = 0; i < 4; ++i) {
        int ra = wm * 64 + i * 16 + col16;
        int ca = ((ks * 4 + quad) ^ (ra & 7)) * 8;
        af[i] = *(const short8*)(As + ra * 64 + ca);
        // paired mapping: j={0,1} -> d in [wn*32, wn*32+32); j={2,3} -> +64
        int rb = wn * 32 + (i & 1) * 16 + (i >> 1) * 64 + col16;
        int cb = ((ks * 4 + quad) ^ (rb & 7)) * 8;
        bf[i] = *(const short8*)(Bs + rb * 64 + cb);
      }
      #pragma unroll
      for (int i = 0; i < 4; ++i)
        #pragma unroll
        for (int j = 0; j < 4; ++j)
          acc[i][j] = __builtin_amdgcn_mfma_f32_16x16x32_bf16(af[i], bf[j], acc[i][j], 0, 0, 0);
    }
  }

  // fence: epilogue code stays below the main loop
  __builtin_amdgcn_sched_barrier(0);

  // -------- fused epilogue (two-phase for all regions) --------
  const int region = n0 >> 11;           // 0=Q, 1=K, 2=V
  const int h   = (n0 & 2047) >> 7;      // head
  const int b   = m0 >> 11;              // batch (BM=128 never straddles b)
  const int t0l = m0 & 2047;             // token base within batch
  const int bh  = b * H_ + h;

  __syncthreads();   // all waves done reading As/Bs from the main loop

  if (region < 2) {
    // ---- Q/K phase 1: acc -> S[t][d] bf16, chunk-swizzled; acc dies here.
    // Wave writes per (i,j,r) tile one full 128B bank period (8 slots x 16B)
    // -> 2 lanes/bank = free.
    #pragma unroll
    for (int i = 0; i < 4; ++i) {
      int tlb = wm * 64 + i * 16 + quad * 4;          // local token 0..127
      #pragma unroll
      for (int j = 0; j < 4; ++j) {
        int d = wn * 32 + (j & 1) * 16 + (j >> 1) * 64 + col16;
        #pragma unroll
        for (int r = 0; r < 4; ++r) {
          int t = tlb + r;
          int ch = (d >> 3) ^ (t & 15);
          S[t * 128 + ch * 8 + (d & 7)] = f2bf(acc[i][j][r]);
        }
      }
    }
    __syncthreads();
    // ---- Q/K phase 2: 2 threads/row; RoPE pair (dlo, dlo+64) both live in
    // this thread's chunks (hf splits lo-half into [0,32) / [32,64)).
    unsigned short* dst = region ? k_r : q_r;
    const float scl = region ? 1.0f : 0.1275174117f;  // Q: (1/sqrt(128))*log2(e)
    int t = tid >> 1, hf = tid & 1;
    int tg = t0l + t;
    size_t ob = (size_t)(bh * T_ + tg) * D_;
    #pragma unroll
    for (int cc = 0; cc < 4; ++cc) {
      int dlo = hf * 32 + cc * 8;                     // 0..63 (lo half)
      int clo = dlo >> 3, chi = clo + 8;
      short8 lo8 = *(const short8*)(S + t * 128 + ((clo ^ (t & 15)) << 3));
      short8 hi8 = *(const short8*)(S + t * 128 + ((chi ^ (t & 15)) << 3));
      const float4_* tp = (const float4_*)(cst + (size_t)tg * 64 + dlo);
      float4_ tq0 = tp[0], tq1 = tp[1], tq2 = tp[2], tq3 = tp[3];
      short8 olo, ohi;
      #pragma unroll
      for (int e = 0; e < 2; ++e) {
        float lo = bf2f((unsigned short)lo8[e]), hi = bf2f((unsigned short)hi8[e]);
        float cs = tq0[e * 2], sn = tq0[e * 2 + 1];
        olo[e] = (short)f2bf((lo * cs - hi * sn) * scl);
        ohi[e] = (short)f2bf((lo * sn + hi * cs) * scl);
      }
      #pragma unroll
      for (int e = 0; e < 2; ++e) {
        float lo = bf2f((unsigned short)lo8[2 + e]), hi = bf2f((unsigned short)hi8[2 + e]);
        float cs = tq1[e * 2], sn = tq1[e * 2 + 1];
        olo[2 + e] = (short)f2bf((lo * cs - hi * sn) * scl);
        ohi[2 + e] = (short)f2bf((lo * sn + hi * cs) * scl);
      }
      #pragma unroll
      for (int e = 0; e < 2; ++e) {
        float lo = bf2f((unsigned short)lo8[4 + e]), hi = bf2f((unsigned short)hi8[4 + e]);
        float cs = tq2[e * 2], sn = tq2[e * 2 + 1];
        olo[4 + e] = (short)f2bf((lo * cs - hi * sn) * scl);
        ohi[4 + e] = (short)f2bf((lo * sn + hi * cs) * scl);
      }
      #pragma unroll
      for (int e = 0; e < 2; ++e) {
        float lo = bf2f((unsigned short)lo8[6 + e]), hi = bf2f((unsigned short)hi8[6 + e]);
        float cs = tq3[e * 2], sn = tq3[e * 2 + 1];
        olo[6 + e] = (short)f2bf((lo * cs - hi * sn) * scl);
        ohi[6 + e] = (short)f2bf((lo * sn + hi * cs) * scl);
      }
      *(short8*)(dst + ob + dlo)      = olo;
      *(short8*)(dst + ob + dlo + 64) = ohi;
    }
  } else {
    // ---- V: transpose via LDS (reuse S, 32 KB = exactly the 128x128 bf16 tile)
    #pragma unroll
    for (int i = 0; i < 4; ++i) {
      int tlb = wm * 64 + i * 16 + quad * 4;          // local token 0..127
      #pragma unroll
      for (int j = 0; j < 4; ++j) {
        int d = wn * 32 + (j & 1) * 16 + (j >> 1) * 64 + col16;
        #pragma unroll
        for (int r = 0; r < 4; ++r) {
          int t = tlb + r;
          int ch = (t >> 3) ^ (d & 15);               // chunk swizzle (~2-way)
          S[d * 128 + ch * 8 + (t & 7)] = f2bf(acc[i][j][r]);
        }
      }
    }
    __syncthreads();
    // coalesced write: 2 threads per d-row, 128 B each
    int drow = tid >> 1, hf = tid & 1;
    size_t gb = (size_t)(bh * D_ + drow) * T_ + t0l + hf * 64;
    #pragma unroll
    for (int cc = 0; cc < 8; ++cc) {
      int ch = (hf * 8 + cc) ^ (drow & 15);
      *(short8*)(v_t + gb + cc * 8) = *(const short8*)(S + drow * 128 + ch * 8);
    }
  }
}

// ------------------------------------------------------- flash attention v3
// (frozen)  Br=128, 512 threads, dbuf K/V staging, log2-domain online softmax,
// wave-uniform diagonal skip, XCD-local heads.
__global__ __launch_bounds__(512) void attn_fwd(const unsigned short* __restrict__ q_r,
                                                const unsigned short* __restrict__ k_r,
                                                const unsigned short* __restrict__ v_t,
                                                unsigned short* __restrict__ Ob) {
  __shared__ __align__(16) unsigned short Ks[2][64 * 128];   // [s][d] swizzled, dbuf
  __shared__ __align__(16) unsigned short Vts[2][128 * 64];  // [d][s] swizzled, dbuf
  __shared__ __align__(16) unsigned short Ps[128 * 64];      // [qrow][s] swizzled
  const int pairb = blockIdx.x >> 5;   // 0..7
  const int bh    = blockIdx.x & 31;   // low bits -> XCD locality by head
  const int tid  = threadIdx.x;
  const int lane = tid & 63;
  const int col16 = lane & 15, quad = lane >> 4;
  const int wave = tid >> 6;           // 0..7
  const float NEG_INF = -__builtin_inff();
  const int b = bh >> 4, h = bh & 15;
  const int qlr = wave * 16 + col16;   // this lane's q row within the 128-tile

  #pragma unroll 1
  for (int half = 0; half < 2; ++half) {
    const int qt = half ? (15 - pairb) : pairb;   // 128-row q tile index
    const int q0 = qt * 128;
    const int njt = 2 * qt + 2;                   // 64-row kv tiles

    // Q frags (B-operand): B[k=d][n=qrow], 8 contiguous d per lane (pre-scaled)
    short8 qf[4];
    const unsigned short* qp = q_r + (size_t)(bh * T_ + q0 + qlr) * D_;
    #pragma unroll
    for (int ks = 0; ks < 4; ++ks) qf[ks] = *(const short8*)(qp + ks * 32 + quad * 8);

    float4_ oacc[8] = {};
    float m_i = NEG_INF, l_i = 0.f;

    __syncthreads();   // WAR: prior half's reads complete before restage

    const unsigned short* kbase = k_r + (size_t)bh * T_ * D_;
    const unsigned short* vbase = v_t + (size_t)bh * D_ * T_;
    #define STAGE(JT, BUF)                                                        \
      {                                                                           \
        const unsigned short* kb = kbase + (size_t)(JT) * 64 * D_;                \
        const unsigned short* vb = vbase + (size_t)(JT) * 64;                     \
        unsigned short* kd = &Ks[(BUF)][0];                                       \
        unsigned short* vd = &Vts[(BUF)][0];                                      \
        _Pragma("unroll")                                                         \
        for (int i = 0; i < 2; ++i) {                                             \
          int P = i * 512 + tid;                                                  \
          int krow = P >> 4, kc = (P & 15) ^ (krow & 7);                          \
          async_cp16(kb + krow * D_ + kc * 8, kd + P * 8);                        \
          int vrow = P >> 3, vc = (P & 7) ^ (vrow & 7);                          \
          async_cp16(vb + (size_t)vrow * T_ + vc * 8, vd + P * 8);                \
        }                                                                         \
      }

    STAGE(0, 0);

    #pragma unroll 1
    for (int jt = 0; jt < njt; ++jt) {
      __syncthreads();                    // tile jt landed; prior reads done
      if (jt + 1 < njt) STAGE(jt + 1, (jt + 1) & 1);

      // wave-uniform skip: this wave's 16 q-rows all above (before) this kv tile
      if (jt * 64 > q0 + wave * 16 + 15) continue;

      const unsigned short* KsB  = &Ks[jt & 1][0];
      const unsigned short* VtsB = &Vts[jt & 1][0];

      // S^T tiles: A = K rows, B = Q  (values already in log2-softmax domain)
      float4_ s[4];
      #pragma unroll
      for (int jn = 0; jn < 4; ++jn) {
        float4_ a = {};
        #pragma unroll
        for (int ks = 0; ks < 4; ++ks) {
          int kr = jn * 16 + col16;
          int ch = ((ks * 4 + quad) ^ (kr & 7)) * 8;
          short8 kfr = *(const short8*)(KsB + kr * 128 + ch);
          a = __builtin_amdgcn_mfma_f32_16x16x32_bf16(kfr, qf[ks], a, 0, 0, 0);
        }
        s[jn] = a;
      }
      if (jt * 64 + 63 > q0 + wave * 16) {  // wave-uniform partial-mask branch
        #pragma unroll
        for (int jn = 0; jn < 4; ++jn)
          #pragma unroll
          for (int r = 0; r < 4; ++r)
            if (jt * 64 + jn * 16 + quad * 4 + r > q0 + qlr) s[jn][r] = NEG_INF;
      }
      // online softmax (log2 domain); stats per q row = per lane
      float rm = NEG_INF;
      #pragma unroll
      for (int jn = 0; jn < 4; ++jn)
        #pragma unroll
        for (int r = 0; r < 4; ++r) rm = fmaxf(rm, s[jn][r]);
      rm = fmaxf(rm, __shfl_xor(rm, 16));
      rm = fmaxf(rm, __shfl_xor(rm, 32));
      float m_new = fmaxf(m_i, rm);
      float alpha = exp2f(m_i - m_new);
      float rs = 0.f;
      #pragma unroll
      for (int jn = 0; jn < 4; ++jn)
        #pragma unroll
        for (int r = 0; r < 4; ++r) {
          float pv = exp2f(s[jn][r] - m_new);
          s[jn][r] = pv;
          rs += pv;
        }
      rs += __shfl_xor(rs, 16);
      rs += __shfl_xor(rs, 32);
      l_i = l_i * alpha + rs;
      m_i = m_new;
      #pragma unroll
      for (int dt = 0; dt < 8; ++dt) oacc[dt] *= alpha;

      // P -> LDS (wave-private rows), packed bf16
      #pragma unroll
      for (int jn = 0; jn < 4; ++jn) {
        short4_ pkv;
        pk2(pkv, 0, s[jn][0], s[jn][1]);
        pk2(pkv, 1, s[jn][2], s[jn][3]);
        int c0 = jn * 16 + quad * 4;
        int ch = (c0 >> 3) ^ (qlr & 7);
        *(short4_*)(Ps + qlr * 64 + ch * 8 + (c0 & 7)) = pkv;
      }
      __builtin_amdgcn_s_waitcnt(0xC07F);  // lgkmcnt(0): own P writes -> own reads

      // O^T += V^T · P^T : A = Vts (m=d), B = Ps rows (n=qrow)
      short8 pf[2];
      #pragma unroll
      for (int ks2 = 0; ks2 < 2; ++ks2) {
        int ch = ((ks2 * 4 + quad) ^ (qlr & 7)) * 8;
        pf[ks2] = *(const short8*)(Ps + qlr * 64 + ch);
      }
      #pragma unroll
      for (int dt = 0; dt < 8; ++dt)
        #pragma unroll
        for (int ks2 = 0; ks2 < 2; ++ks2) {
          int vr = dt * 16 + col16;
          int ch = ((ks2 * 4 + quad) ^ (vr & 7)) * 8;
          short8 vf = *(const short8*)(VtsB + vr * 64 + ch);
          oacc[dt] = __builtin_amdgcn_mfma_f32_16x16x32_bf16(vf, pf[ks2], oacc[dt], 0, 0, 0);
        }
    }

    // epilogue: O^T C-layout col=lane&15=qrow, row=quad*4+r=d
    float inv_l = 1.0f / l_i;
    size_t ob = (size_t)(b * T_ + q0 + qlr) * C_ + h * D_;
    #pragma unroll
    for (int dt = 0; dt < 8; ++dt) {
      short4_ o4;
      pk2(o4, 0, oacc[dt][0] * inv_l, oacc[dt][1] * inv_l);
      pk2(o4, 1, oacc[dt][2] * inv_l, oacc[dt][3] * inv_l);
      *(short4_*)(Ob + ob + dt * 16 + quad * 4) = o4;
    }
    #undef STAGE
  }
}

// ---------------------------------------------------------------- launcher
extern "C" void kernel_launch(void* const* d_in, const int* in_sizes, int n_in,
                              void* d_out, int out_size, void* d_ws, size_t ws_size,
                              hipStream_t stream) {
  const float* x     = (const float*)d_in[0];
  const float* Wqkv  = (const float*)d_in[1];
  const float* Wproj = (const float*)d_in[2];
  const int*   sp    = (const int*)d_in[3];
  float* out = (float*)d_out;

  unsigned short* ws     = (unsigned short*)d_ws;
  unsigned short* xb     = ws;                    //  8,388,608
  unsigned short* wqkvb  = xb + 8388608;          // 12,582,912
  unsigned short* wprojb = wqkvb + 12582912;      //  4,194,304
  unsigned short* q_r    = wprojb + 4194304;      //  8,388,608
  unsigned short* k_r    = q_r + 8388608;         //  8,388,608
  unsigned short* v_t    = k_r + 8388608;         //  8,388,608
  float2*         cstab  = (float2*)(v_t + 8388608);  // 131,072 float2 (1 MB)
  unsigned short* Obuf   = xb;                    // alias: xb dead after GEMM1

  // bf16 conversion + interleaved trig table in one launch
  cvt_all<<<12800, 256, 0, stream>>>(x, Wqkv, Wproj, sp, ws, cstab);

  // QKV projection with fused RoPE/split/V-transpose (two-phase LDS epilogue)
  gemm_qkv<<<dim3(48, 32), 256, 0, stream>>>(xb, wqkvb, cstab, q_r, k_r, v_t);

  attn_fwd<<<dim3(256), 512, 0, stream>>>(q_r, k_r, v_t, Obuf);

  gemm_bt<true><<<dim3(16, 32), 256, 0, stream>>>(Obuf, wprojb, (void*)out, BT_, C_, C_);
}

// Round 8
// 366.130 us; speedup vs baseline: 1.0398x; 1.0398x over previous
//
#include <hip/hip_runtime.h>
#include <hip/hip_bf16.h>
#include <stdint.h>
#include <math.h>

// Problem constants
#define B_    2
#define T_    2048
#define C_    2048
#define H_    16
#define D_    128
#define NQKV  6144      // 3*C
#define BT_   4096      // B*T

typedef __attribute__((ext_vector_type(8))) short  short8;   // 8 bf16 (4 VGPR) MFMA A/B frag
typedef __attribute__((ext_vector_type(4))) short  short4_;  // 4 bf16 (8B)
typedef __attribute__((ext_vector_type(4))) float  float4_;  // MFMA C/D frag

__device__ __forceinline__ unsigned short f2bf(float f) {
  union { float f; unsigned int u; } v; v.f = f;
  unsigned int u = v.u;
  return (unsigned short)((u + 0x7FFFu + ((u >> 16) & 1u)) >> 16);  // RNE
}
__device__ __forceinline__ float bf2f(unsigned short u) {
  union { unsigned int i; float f; } v; v.i = ((unsigned int)u) << 16;
  return v.f;
}
// packed fp32x2 -> bf16x2
__device__ __forceinline__ void pk2(short4_& dst, int idx2, float a, float b) {
  union { __hip_bfloat162 h2; struct { short x, y; } s; } u;
  u.h2 = __float22bfloat162_rn(make_float2(a, b));
  dst[idx2 * 2]     = u.s.x;
  dst[idx2 * 2 + 1] = u.s.y;
}

// async global->LDS, 16B per lane.  HW dest = wave-uniform base + lane*16,
// so LDS offsets must be contiguous in thread order (they are: base + tid*16).
__device__ __forceinline__ void async_cp16(const unsigned short* g, unsigned short* l) {
  __builtin_amdgcn_global_load_lds((__attribute__((address_space(1))) void*)g,
                                   (__attribute__((address_space(3))) void*)l,
                                   16, 0, 0);
}

// ----------------------------- fused fp32->bf16 (all 3 inputs) + trig tables
// Blocks 0..12287: bf16 conversion.  Blocks 12288..12799: RoPE trig tables
// ct/st[t*64+d] = cos/sin((sp+t) * 10000^(-d/64)).  Accurate sinf/cosf live
// HERE (tiny register footprint -> inlined; round-2 lesson: outlined trig
// inside the fat GEMM caused a scratch-write storm).
__global__ __launch_bounds__(256) void cvt_all(const float* __restrict__ x,
                                               const float* __restrict__ wqkv,
                                               const float* __restrict__ wproj,
                                               const int* __restrict__ sp_ptr,
                                               unsigned short* __restrict__ out,
                                               float* __restrict__ ct,
                                               float* __restrict__ st) {
  if (blockIdx.x >= 12288) {
    int j = (blockIdx.x - 12288) * 256 + threadIdx.x;   // 0..131071
    int d = j & 63;
    const float L2F = -0.20762050593046013f;  // -log2(10000)/64
    float fr = exp2f((float)d * L2F);
    float ang = (float)(sp_ptr[0] + (j >> 6)) * fr;
    ct[j] = cosf(ang);
    st[j] = sinf(ang);
    return;
  }
  int i = (blockIdx.x * 256 + threadIdx.x) * 8;   // 0 .. 25165824-8
  const float* src; int off;
  if (i < 8388608)       { src = x;     off = i; }
  else if (i < 20971520) { src = wqkv;  off = i - 8388608; }
  else                   { src = wproj; off = i - 20971520; }
  const float4_* p = (const float4_*)(src + off);
  float4_ a = p[0], b = p[1];
  short8 o;
  o[0] = (short)f2bf(a[0]); o[1] = (short)f2bf(a[1]);
  o[2] = (short)f2bf(a[2]); o[3] = (short)f2bf(a[3]);
  o[4] = (short)f2bf(b[0]); o[5] = (short)f2bf(b[1]);
  o[6] = (short)f2bf(b[2]); o[7] = (short)f2bf(b[3]);
  *(short8*)(out + i) = o;
}

// ------------------------------------------------------- GEMM  C = A * B^T
// (frozen m97-structure 128x128 kernel — used for the projection GEMM)
template <bool F32OUT>
__global__ __launch_bounds__(256) void gemm_bt(const unsigned short* __restrict__ A,
                                               const unsigned short* __restrict__ Bm,
                                               void* __restrict__ Cout,
                                               int M, int N, int K) {
  __shared__ __align__(16) unsigned short As[128 * 64];
  __shared__ __align__(16) unsigned short Bs[128 * 64];
  const int tid  = threadIdx.x;
  const int lane = tid & 63;
  const int col16 = lane & 15, quad = lane >> 4;
  const int wave = tid >> 6;
  const int wm = wave >> 1, wn = wave & 1;
  const int m0 = blockIdx.y * 128, n0 = blockIdx.x * 128;

  float4_ acc[4][4] = {};

  #pragma unroll 1
  for (int k0 = 0; k0 < K; k0 += 64) {
    __syncthreads();
    #pragma unroll
    for (int i = 0; i < 4; ++i) {
      int P   = i * 256 + tid;
      int row = P >> 3;                    // tile row 0..127
      int kc  = (P & 7) ^ (row & 7);       // logical chunk for this phys slot
      async_cp16(A  + (size_t)(m0 + row) * K + k0 + kc * 8, As + P * 8);
      async_cp16(Bm + (size_t)(n0 + row) * K + k0 + kc * 8, Bs + P * 8);
    }
    __syncthreads();
    #pragma unroll
    for (int ks = 0; ks < 2; ++ks) {
      short8 af[4], bf[4];
      #pragma unroll
      for (int i = 0; i < 4; ++i) {
        int ra = wm * 64 + i * 16 + col16;
        int ca = ((ks * 4 + quad) ^ (ra & 7)) * 8;
        af[i] = *(const short8*)(As + ra * 64 + ca);
        int rb = wn * 64 + i * 16 + col16;
        int cb = ((ks * 4 + quad) ^ (rb & 7)) * 8;
        bf[i] = *(const short8*)(Bs + rb * 64 + cb);
      }
      #pragma unroll
      for (int i = 0; i < 4; ++i)
        #pragma unroll
        for (int j = 0; j < 4; ++j)
          acc[i][j] = __builtin_amdgcn_mfma_f32_16x16x32_bf16(af[i], bf[j], acc[i][j], 0, 0, 0);
    }
  }

  // epilogue: C/D layout col=lane&15 (n), row=quad*4+reg (m)
  #pragma unroll
  for (int i = 0; i < 4; ++i) {
    int mg = m0 + wm * 64 + i * 16 + quad * 4;
    #pragma unroll
    for (int j = 0; j < 4; ++j) {
      int ng = n0 + wn * 64 + j * 16 + col16;
      #pragma unroll
      for (int r = 0; r < 4; ++r) {
        if constexpr (F32OUT)
          ((float*)Cout)[(size_t)(mg + r) * N + ng] = acc[i][j][r];
        else
          ((unsigned short*)Cout)[(size_t)(mg + r) * N + ng] = f2bf(acc[i][j][r]);
      }
    }
  }
}

// ---------------------------------------- GEMM1 + fused RoPE/split/V-transpose
// Round-3 configuration EXACTLY (best measured fused variant: 137 us, VGPR
// 112, 4 blk/CU).  Rounds 4-7 tried to cut VGPR below 102 (launch-bounds cap,
// sched_barrier fences, two-phase LDS epilogue) — all regressed or were
// neutral; the RoPE-pair epilogue's acc live-range sets a 112-VGPR floor.
// Accepted.  B-fragment row mapping per j: rb = wn*32+(j&1)*16+(j>>1)*64+c16,
// so acc[i][j]/acc[i][j+2] hold the RoPE pair (d, d+64) in the same lane.
// Each 128-wide n-tile is one head of Q, K or V (block-uniform epilogue mode).
__global__ __launch_bounds__(256) void gemm_qkv(const unsigned short* __restrict__ A,
                                                const unsigned short* __restrict__ Bm,
                                                const float* __restrict__ ct,
                                                const float* __restrict__ st,
                                                unsigned short* __restrict__ q_r,
                                                unsigned short* __restrict__ k_r,
                                                unsigned short* __restrict__ v_t) {
  __shared__ __align__(16) unsigned short S[16384];  // As = S[0:8192), Bs = S[8192:16384)
  unsigned short* As = S;
  unsigned short* Bs = S + 8192;
  const int tid  = threadIdx.x;
  const int lane = tid & 63;
  const int col16 = lane & 15, quad = lane >> 4;
  const int wave = tid >> 6;
  const int wm = wave >> 1, wn = wave & 1;
  const int m0 = blockIdx.y * 128, n0 = blockIdx.x * 128;

  float4_ acc[4][4] = {};

  #pragma unroll 1
  for (int k0 = 0; k0 < C_; k0 += 64) {
    __syncthreads();
    #pragma unroll
    for (int i = 0; i < 4; ++i) {
      int P   = i * 256 + tid;
      int row = P >> 3;
      int kc  = (P & 7) ^ (row & 7);
      async_cp16(A  + (size_t)(m0 + row) * C_ + k0 + kc * 8, As + P * 8);
      async_cp16(Bm + (size_t)(n0 + row) * C_ + k0 + kc * 8, Bs + P * 8);
    }
    __syncthreads();
    #pragma unroll
    for (int ks = 0; ks < 2; ++ks) {
      short8 af[4], bf[4];
      #pragma unroll
      for (int i = 0; i < 4; ++i) {
        int ra = wm * 64 + i * 16 + col16;
        int ca = ((ks * 4 + quad) ^ (ra & 7)) * 8;
        af[i] = *(const short8*)(As + ra * 64 + ca);
        // paired mapping: j={0,1} -> d in [wn*32, wn*32+32); j={2,3} -> +64
        int rb = wn * 32 + (i & 1) * 16 + (i >> 1) * 64 + col16;
        int cb = ((ks * 4 + quad) ^ (rb & 7)) * 8;
        bf[i] = *(const short8*)(Bs + rb * 64 + cb);
      }
      #pragma unroll
      for (int i = 0; i < 4; ++i)
        #pragma unroll
        for (int j = 0; j < 4; ++j)
          acc[i][j] = __builtin_amdgcn_mfma_f32_16x16x32_bf16(af[i], bf[j], acc[i][j], 0, 0, 0);
    }
  }

  // -------- fused epilogue --------
  const int region = n0 >> 11;           // 0=Q, 1=K, 2=V
  const int h   = (n0 & 2047) >> 7;      // head
  const int b   = m0 >> 11;              // batch (BM=128 never straddles b)
  const int t0l = m0 & 2047;             // token base within batch
  const int bh  = b * H_ + h;

  if (region < 2) {
    // ---- Q/K: register-local RoPE (pair (d, d+64) = acc[i][jl] / acc[i][jl+2])
    unsigned short* dst = region ? k_r : q_r;
    const float scl = region ? 1.0f : 0.1275174117f;  // Q: (1/sqrt(128))*log2(e)
    #pragma unroll
    for (int i = 0; i < 4; ++i) {
      int tl = t0l + wm * 64 + i * 16 + quad * 4;     // token (local to batch), +r below
      #pragma unroll
      for (int jl = 0; jl < 2; ++jl) {
        int d = wn * 32 + jl * 16 + col16;            // 0..63 (lo half)
        size_t ob = (size_t)(bh * T_ + tl) * D_ + d;
        int ti = tl * 64 + d;
        #pragma unroll
        for (int r = 0; r < 4; ++r) {
          float cs = ct[ti + r * 64], sn = st[ti + r * 64];
          float lo = acc[i][jl][r], hi = acc[i][jl + 2][r];
          dst[ob + (size_t)r * D_]      = f2bf((lo * cs - hi * sn) * scl);
          dst[ob + (size_t)r * D_ + 64] = f2bf((lo * sn + hi * cs) * scl);
        }
      }
    }
  } else {
    // ---- V: transpose via LDS (reuse S, 32 KB = exactly the 128x128 bf16 tile)
    __syncthreads();   // all waves done reading As/Bs from the main loop
    #pragma unroll
    for (int i = 0; i < 4; ++i) {
      int tlb = wm * 64 + i * 16 + quad * 4;          // local token 0..127
      #pragma unroll
      for (int j = 0; j < 4; ++j) {
        int d = wn * 32 + (j & 1) * 16 + (j >> 1) * 64 + col16;
        #pragma unroll
        for (int r = 0; r < 4; ++r) {
          int t = tlb + r;
          int ch = (t >> 3) ^ (d & 15);               // chunk swizzle (~2-way)
          S[d * 128 + ch * 8 + (t & 7)] = f2bf(acc[i][j][r]);
        }
      }
    }
    __syncthreads();
    // coalesced write: 2 threads per d-row, 128 B each
    int drow = tid >> 1, hf = tid & 1;
    size_t gb = (size_t)(bh * D_ + drow) * T_ + t0l + hf * 64;
    #pragma unroll
    for (int cc = 0; cc < 8; ++cc) {
      int ch = (hf * 8 + cc) ^ (drow & 15);
      *(short8*)(v_t + gb + cc * 8) = *(const short8*)(S + drow * 128 + ch * 8);
    }
  }
}

// ------------------------------------------------------- flash attention v4
// Round-8 change: 1 q-tile per block (grid 512 = 16 qt x 32 bh) instead of
// the (qt, 15-qt) pair per block.  LDS 80 KB x 2 = 160 KB/CU and
// __launch_bounds__(512,4) (VGPR cap 128) -> TWO co-resident blocks per CU,
// so one block's MFMA/softmax overlaps the other's barrier+staging drains
// (the m114 mechanism — previously absent at 1 block/CU, MFMA pipe ~4% busy).
// qt = (g<8 ? g : 23-g): under round-robin CU assignment blocks b and b+256
// co-reside and their qt's sum to 15 -> uniform 17 tiles per CU.
__global__ __launch_bounds__(512, 4) void attn_fwd(const unsigned short* __restrict__ q_r,
                                                   const unsigned short* __restrict__ k_r,
                                                   const unsigned short* __restrict__ v_t,
                                                   unsigned short* __restrict__ Ob) {
  __shared__ __align__(16) unsigned short Ks[2][64 * 128];   // [s][d] swizzled, dbuf
  __shared__ __align__(16) unsigned short Vts[2][128 * 64];  // [d][s] swizzled, dbuf
  __shared__ __align__(16) unsigned short Ps[128 * 64];      // [qrow][s] swizzled
  const int g     = blockIdx.x >> 5;   // 0..15
  const int bh    = blockIdx.x & 31;   // low bits -> XCD locality by head
  const int qt    = (g < 8) ? g : 23 - g;   // balanced co-residency pairing
  const int tid  = threadIdx.x;
  const int lane = tid & 63;
  const int col16 = lane & 15, quad = lane >> 4;
  const int wave = tid >> 6;           // 0..7
  const float NEG_INF = -__builtin_inff();
  const int b = bh >> 4, h = bh & 15;
  const int qlr = wave * 16 + col16;   // this lane's q row within the 128-tile

  const int q0 = qt * 128;
  const int njt = 2 * qt + 2;                   // 64-row kv tiles

  // Q frags (B-operand): B[k=d][n=qrow], 8 contiguous d per lane (pre-scaled)
  short8 qf[4];
  const unsigned short* qp = q_r + (size_t)(bh * T_ + q0 + qlr) * D_;
  #pragma unroll
  for (int ks = 0; ks < 4; ++ks) qf[ks] = *(const short8*)(qp + ks * 32 + quad * 8);

  float4_ oacc[8] = {};
  float m_i = NEG_INF, l_i = 0.f;

  const unsigned short* kbase = k_r + (size_t)bh * T_ * D_;
  const unsigned short* vbase = v_t + (size_t)bh * D_ * T_;
  #define STAGE(JT, BUF)                                                        \
    {                                                                           \
      const unsigned short* kb = kbase + (size_t)(JT) * 64 * D_;                \
      const unsigned short* vb = vbase + (size_t)(JT) * 64;                     \
      unsigned short* kd = &Ks[(BUF)][0];                                       \
      unsigned short* vd = &Vts[(BUF)][0];                                      \
      _Pragma("unroll")                                                         \
      for (int i = 0; i < 2; ++i) {                                             \
        int P = i * 512 + tid;                                                  \
        int krow = P >> 4, kc = (P & 15) ^ (krow & 7);                          \
        async_cp16(kb + krow * D_ + kc * 8, kd + P * 8);                        \
        int vrow = P >> 3, vc = (P & 7) ^ (vrow & 7);                           \
        async_cp16(vb + (size_t)vrow * T_ + vc * 8, vd + P * 8);                \
      }                                                                         \
    }

  STAGE(0, 0);

  #pragma unroll 1
  for (int jt = 0; jt < njt; ++jt) {
    __syncthreads();                    // tile jt landed; prior reads done
    if (jt + 1 < njt) STAGE(jt + 1, (jt + 1) & 1);

    // wave-uniform skip: this wave's 16 q-rows all above (before) this kv tile
    if (jt * 64 > q0 + wave * 16 + 15) continue;

    const unsigned short* KsB  = &Ks[jt & 1][0];
    const unsigned short* VtsB = &Vts[jt & 1][0];

    // S^T tiles: A = K rows, B = Q  (values already in log2-softmax domain)
    float4_ s[4];
    #pragma unroll
    for (int jn = 0; jn < 4; ++jn) {
      float4_ a = {};
      #pragma unroll
      for (int ks = 0; ks < 4; ++ks) {
        int kr = jn * 16 + col16;
        int ch = ((ks * 4 + quad) ^ (kr & 7)) * 8;
        short8 kfr = *(const short8*)(KsB + kr * 128 + ch);
        a = __builtin_amdgcn_mfma_f32_16x16x32_bf16(kfr, qf[ks], a, 0, 0, 0);
      }
      s[jn] = a;
    }
    if (jt * 64 + 63 > q0 + wave * 16) {  // wave-uniform partial-mask branch
      #pragma unroll
      for (int jn = 0; jn < 4; ++jn)
        #pragma unroll
        for (int r = 0; r < 4; ++r)
          if (jt * 64 + jn * 16 + quad * 4 + r > q0 + qlr) s[jn][r] = NEG_INF;
    }
    // online softmax (log2 domain); stats per q row = per lane
    float rm = NEG_INF;
    #pragma unroll
    for (int jn = 0; jn < 4; ++jn)
      #pragma unroll
      for (int r = 0; r < 4; ++r) rm = fmaxf(rm, s[jn][r]);
    rm = fmaxf(rm, __shfl_xor(rm, 16));
    rm = fmaxf(rm, __shfl_xor(rm, 32));
    float m_new = fmaxf(m_i, rm);
    float alpha = exp2f(m_i - m_new);
    float rs = 0.f;
    #pragma unroll
    for (int jn = 0; jn < 4; ++jn)
      #pragma unroll
      for (int r = 0; r < 4; ++r) {
        float pv = exp2f(s[jn][r] - m_new);
        s[jn][r] = pv;
        rs += pv;
      }
    rs += __shfl_xor(rs, 16);
    rs += __shfl_xor(rs, 32);
    l_i = l_i * alpha + rs;
    m_i = m_new;
    #pragma unroll
    for (int dt = 0; dt < 8; ++dt) oacc[dt] *= alpha;

    // P -> LDS (wave-private rows), packed bf16
    #pragma unroll
    for (int jn = 0; jn < 4; ++jn) {
      short4_ pkv;
      pk2(pkv, 0, s[jn][0], s[jn][1]);
      pk2(pkv, 1, s[jn][2], s[jn][3]);
      int c0 = jn * 16 + quad * 4;
      int ch = (c0 >> 3) ^ (qlr & 7);
      *(short4_*)(Ps + qlr * 64 + ch * 8 + (c0 & 7)) = pkv;
    }
    __builtin_amdgcn_s_waitcnt(0xC07F);  // lgkmcnt(0): own P writes -> own reads

    // O^T += V^T · P^T : A = Vts (m=d), B = Ps rows (n=qrow)
    short8 pf[2];
    #pragma unroll
    for (int ks2 = 0; ks2 < 2; ++ks2) {
      int ch = ((ks2 * 4 + quad) ^ (qlr & 7)) * 8;
      pf[ks2] = *(const short8*)(Ps + qlr * 64 + ch);
    }
    #pragma unroll
    for (int dt = 0; dt < 8; ++dt)
      #pragma unroll
      for (int ks2 = 0; ks2 < 2; ++ks2) {
        int vr = dt * 16 + col16;
        int ch = ((ks2 * 4 + quad) ^ (vr & 7)) * 8;
        short8 vf = *(const short8*)(VtsB + vr * 64 + ch);
        oacc[dt] = __builtin_amdgcn_mfma_f32_16x16x32_bf16(vf, pf[ks2], oacc[dt], 0, 0, 0);
      }
  }

  // epilogue: O^T C-layout col=lane&15=qrow, row=quad*4+r=d
  float inv_l = 1.0f / l_i;
  size_t ob = (size_t)(b * T_ + q0 + qlr) * C_ + h * D_;
  #pragma unroll
  for (int dt = 0; dt < 8; ++dt) {
    short4_ o4;
    pk2(o4, 0, oacc[dt][0] * inv_l, oacc[dt][1] * inv_l);
    pk2(o4, 1, oacc[dt][2] * inv_l, oacc[dt][3] * inv_l);
    *(short4_*)(Ob + ob + dt * 16 + quad * 4) = o4;
  }
  #undef STAGE
}

// ---------------------------------------------------------------- launcher
extern "C" void kernel_launch(void* const* d_in, const int* in_sizes, int n_in,
                              void* d_out, int out_size, void* d_ws, size_t ws_size,
                              hipStream_t stream) {
  const float* x     = (const float*)d_in[0];
  const float* Wqkv  = (const float*)d_in[1];
  const float* Wproj = (const float*)d_in[2];
  const int*   sp    = (const int*)d_in[3];
  float* out = (float*)d_out;

  unsigned short* ws     = (unsigned short*)d_ws;
  unsigned short* xb     = ws;                    //  8,388,608
  unsigned short* wqkvb  = xb + 8388608;          // 12,582,912
  unsigned short* wprojb = wqkvb + 12582912;      //  4,194,304
  unsigned short* q_r    = wprojb + 4194304;      //  8,388,608
  unsigned short* k_r    = q_r + 8388608;         //  8,388,608
  unsigned short* v_t    = k_r + 8388608;         //  8,388,608
  float*          ctab   = (float*)(v_t + 8388608);  // 131,072 f32
  float*          stab   = ctab + 131072;            // 131,072 f32
  unsigned short* Obuf   = xb;                    // alias: xb dead after GEMM1

  // bf16 conversion + trig tables in one launch (trig blocks at the tail)
  cvt_all<<<12800, 256, 0, stream>>>(x, Wqkv, Wproj, sp, ws, ctab, stab);

  // QKV projection with fused RoPE/split/V-transpose (round-3 config)
  gemm_qkv<<<dim3(48, 32), 256, 0, stream>>>(xb, wqkvb, ctab, stab, q_r, k_r, v_t);

  // attention: 512 single-tile blocks -> 2 co-resident blocks/CU
  attn_fwd<<<dim3(512), 512, 0, stream>>>(q_r, k_r, v_t, Obuf);

  gemm_bt<true><<<dim3(16, 32), 256, 0, stream>>>(Obuf, wprojb, (void*)out, BT_, C_, C_);
}